// Round 7
// baseline (16588.960 us; speedup 1.0000x reference)
//
#include <hip/hip_runtime.h>
#include <hip/hip_cooperative_groups.h>
#include <math.h>

typedef unsigned int u32x4 __attribute__((ext_vector_type(4)));

constexpr int T = 4096;   // SEQ_LEN
constexpr int R = 2048;   // RES_SIZE
constexpr int J = 128;    // INPUT_SIZE
constexpr float ONE_MINUS_LEAK = 0.1f;
constexpr float LEAK = 0.9f;
constexpr float INV_SQRT_R = 0.022097086912079608f;  // 1/sqrt(2048)

constexpr int NWG  = 256;          // one WG per CU
constexpr int NREP = 8;            // replicated poll regions
constexpr unsigned SENT = 0xFFFFFFFFu;  // sentinel bit pattern (-NaN)

// ---------------- Kernel A: proj[t][r] = input[t] . W_in[r] + bias[r] -> d_out
__global__ __launch_bounds__(256) void esn_proj_kernel(
    const float* __restrict__ U, const float* __restrict__ Win,
    const float* __restrict__ bias, float* __restrict__ out)
{
    __shared__ float As[16][129];
    __shared__ float Bs[16][129];
    const int tb = blockIdx.x * 16;
    const int rb = blockIdx.y * 16;
    const int tid = threadIdx.x;

    for (int i = tid; i < 16 * J; i += 256) {
        int r = i >> 7, c = i & 127;
        As[r][c] = U[(size_t)(tb + r) * J + c];
        Bs[r][c] = Win[(size_t)(rb + r) * J + c];
    }
    __syncthreads();

    const int ti = tid >> 4;
    const int rj = tid & 15;
    float acc = 0.f;
#pragma unroll
    for (int k = 0; k < J; ++k) acc = fmaf(As[ti][k], Bs[rj][k], acc);
    out[(size_t)(tb + ti) * R + (rb + rj)] = acc + bias[rb + rj];
}

// ---------------- Kernel B: persistent recurrence, 4-buffer sentinel protocol
// 256 WGs x 512 threads; WG w owns rows [8w,8w+8), wave v owns row 8w+v.
// buf[4][NREP][R] bare f32: slot fresh <=> bits != SENT. Publish = ONE 4B
// sc0sc1 store (value is its own validity). Buffer b reused every 4 steps;
// the producer of row r re-arms buf[(t+2)&3][r] to SENT during step t and
// acks it (vmcnt 0) BEFORE publishing x^{t+1} -> any consumer that observed
// x^{t+3} (i.e., entered step t+4) provably sees the reset, so stale values
// can never be mistaken for fresh ones. All traffic sc0sc1 (no XCD/L2
// placement assumptions -- R6's deadlock lesson).
__global__ __launch_bounds__(512, 2) void esn_recur_kernel(
    const float* __restrict__ Wres, float* __restrict__ out,
    unsigned* __restrict__ buf /* [4][NREP][R] */)
{
    const int wg   = blockIdx.x;
    const int tid  = threadIdx.x;
    const int wave = tid >> 6;
    const int lane = tid & 63;
    const int row  = wg * 8 + wave;
    const int grp  = wg & (NREP - 1);

    // Row weights in registers (coalesced: 64 lanes x f32 per k)
    float w[32];
    {
        const float* wr = Wres + (size_t)row * R + lane;
#pragma unroll
        for (int k = 0; k < 32; ++k) w[k] = wr[k * 64];
    }

    __shared__ __align__(16) float xs[2][R];
    float xold = 0.f;   // this row's previous state (used by lane 0)

    for (int t = 0; t < T; ++t) {
        // Prefetch input projection early; latency hides under the poll.
        float proj = 0.f;
        if (lane == 0) proj = out[(size_t)t * R + row];

        // Poll x^{(t)} in our replica: thread owns slots 4tid..4tid+3.
        const unsigned* p =
            buf + ((size_t)((t & 3) * NREP + grp)) * R + 4 * tid;
        u32x4 v;
        while (true) {
            asm volatile(
                "global_load_dwordx4 %0, %1, off sc0 sc1\n\t"
                "s_waitcnt vmcnt(0)"
                : "=&v"(v) : "v"(p) : "memory");
            if (v[0] != SENT && v[1] != SENT &&
                v[2] != SENT && v[3] != SENT) break;
        }
        float* xb = xs[t & 1] + 4 * tid;
        xb[0] = __uint_as_float(v[0]);
        xb[1] = __uint_as_float(v[1]);
        xb[2] = __uint_as_float(v[2]);
        xb[3] = __uint_as_float(v[3]);
        __syncthreads();   // the only barrier per step: stage -> dot join

        // Row dot product: 32 conflict-free LDS reads, 4 FMA chains.
        float a0 = 0.f, a1 = 0.f, a2 = 0.f, a3 = 0.f;
        const float* x = xs[t & 1];
#pragma unroll
        for (int k = 0; k < 8; ++k) {
            a0 = fmaf(w[4 * k + 0], x[(4 * k + 0) * 64 + lane], a0);
            a1 = fmaf(w[4 * k + 1], x[(4 * k + 1) * 64 + lane], a1);
            a2 = fmaf(w[4 * k + 2], x[(4 * k + 2) * 64 + lane], a2);
            a3 = fmaf(w[4 * k + 3], x[(4 * k + 3) * 64 + lane], a3);
        }
        float acc = (a0 + a1) + (a2 + a3);
#pragma unroll
        for (int off = 32; off > 0; off >>= 1)
            acc += __shfl_xor(acc, off);

        if (lane == 0) {
            // 1) Re-arm the buffer that step t+4 will poll (off critical path).
            const size_t rb = (size_t)(((t + 2) & 3) * NREP) * R + row;
#pragma unroll
            for (int g = 0; g < NREP; ++g)
                __hip_atomic_store(&buf[rb + (size_t)g * R], SENT,
                                   __ATOMIC_RELAXED, __HIP_MEMORY_SCOPE_AGENT);
            // 2) Ack the resets BEFORE publishing (ordering proof above).
            asm volatile("s_waitcnt vmcnt(0)" ::: "memory");

            float pre  = acc + proj;          // RES_SCALE = INPUT_SCALE = 1
            float xnew = ONE_MINUS_LEAK * xold + LEAK * erff(pre) * INV_SQRT_R;
            xold = xnew;

            // 3) Publish x^{t+1}: one 4B store per replica, value==validity.
            const unsigned bits = __float_as_uint(xnew);
            const size_t pb = (size_t)(((t + 1) & 3) * NREP) * R + row;
#pragma unroll
            for (int g = 0; g < NREP; ++g)
                __hip_atomic_store(&buf[pb + (size_t)g * R], bits,
                                   __ATOMIC_RELAXED, __HIP_MEMORY_SCOPE_AGENT);
            out[(size_t)t * R + row] = xnew;  // states output
        }
    }
}

extern "C" void kernel_launch(void* const* d_in, const int* in_sizes, int n_in,
                              void* d_out, int out_size, void* d_ws, size_t ws_size,
                              hipStream_t stream) {
    const float* U    = (const float*)d_in[0];  // (4096,128)
    const float* Win  = (const float*)d_in[1];  // (2048,128)
    const float* Wres = (const float*)d_in[2];  // (2048,2048)
    const float* bias = (const float*)d_in[3];  // (2048,)
    float* out = (float*)d_out;                 // (4096,2048)
    unsigned* buf = (unsigned*)d_ws;            // [4][NREP][R] u32

    // buf0 = 0.0f everywhere (valid x^0); buf1..3 = 0xFFFFFFFF (sentinel).
    const size_t bufBytes = (size_t)NREP * R * sizeof(unsigned);
    hipMemsetAsync(buf, 0x00, bufBytes, stream);
    hipMemsetAsync((char*)d_ws + bufBytes, 0xFF, 3 * bufBytes, stream);

    dim3 pgrid(T / 16, R / 16);
    esn_proj_kernel<<<pgrid, dim3(256), 0, stream>>>(U, Win, bias, out);

    void* args[] = { (void*)&Wres, (void*)&out, (void*)&buf };
    hipLaunchCooperativeKernel((const void*)esn_recur_kernel,
                               dim3(NWG), dim3(512), args, 0, stream);
}